// Round 3
// baseline (558.418 us; speedup 1.0000x reference)
//
#include <hip/hip_runtime.h>

#define MM 128
#define NN 128
#define KK 128
#define NBATCH 4
#define ITERS 8
#define WIN 10
#define WSTRIDE 12
#define WSZ (WIN * WIN * WSTRIDE)  // 1200 floats per window
#define MNK (MM * NN * KK)

// full 64-lane butterfly on a (sum, sumsq) pair
__device__ __forceinline__ void bfly2(float& s, float& q) {
  s += __shfl_xor(s, 32, 64); q += __shfl_xor(q, 32, 64);
  s += __shfl_xor(s, 16, 64); q += __shfl_xor(q, 16, 64);
  s += __shfl_xor(s, 8, 64);  q += __shfl_xor(q, 8, 64);
  s += __shfl_xor(s, 4, 64);  q += __shfl_xor(q, 4, 64);
  s += __shfl_xor(s, 2, 64);  q += __shfl_xor(q, 2, 64);
  s += __shfl_xor(s, 1, 64);  q += __shfl_xor(q, 1, 64);
}

// One workgroup per spatial 8^3 block (4096 blocks), 128 threads, and ALL 4
// batches processed CONCURRENTLY per block. The 27*4 conv weights are shared
// across batches in registers (the reason batches live in one block); the 4
// batch windows live in LDS simultaneously (4 x 4.8 KB, single-buffered).
// Why: rounds 0-2 showed a latency-bound kernel (VALU 26%, DS ~30%, HBM 7%,
// occ 20-30%) with a barrier every ~600 cycles and one dependent chain per
// thread. 4 concurrent batches give 4x independent chains per thread (96
// ds_read + 432 FMA per iter, all independent) and 4x fewer barriers.
__global__ __launch_bounds__(128, 2) void gridnet_kernel(
    const float* __restrict__ weight, const float* __restrict__ bias,
    const float* __restrict__ rscale, const float* __restrict__ x,
    float* __restrict__ out) {
  // rows padded 10 -> 12 floats: float2-aligned, 48B row stride
  __shared__ __align__(16) float Wl[NBATCH][WSZ];
  __shared__ __align__(16) float red[2][NBATCH][4];  // [parity][b][{w0s,w0q,w1s,w1q}]
  __shared__ __align__(16) float redH[NBATCH][4];    // halo totals per wave

  const int t = threadIdx.x;
  const int r2 = t & 3, q2 = (t >> 2) & 3, p = t >> 4;
  const int r0 = r2 * 2, q0 = q2 * 2;

  // XCD-bijective swizzle (4096 % 8 == 0): adjacent-bk blocks (sharing 64B
  // weight/x cache lines) land on the same XCD's L2. FETCH 575->139 MB kept.
  const int bx = ((blockIdx.x & 7) << 9) | ((int)blockIdx.x >> 3);
  const int bm = bx >> 8, bn = (bx >> 4) & 15, bk = bx & 15;
  const int gm0 = bm * 8, gn0 = bn * 8, gk0 = bk * 8;
  const int baseg = ((gm0 + p) * NN + (gn0 + q0)) * KK + (gk0 + r0);

  // per-thread weights: w[dq][dr][o], o = i*9 + j*3 + k (long-latency global
  // loads issued first; they drain under the window-load phase)
  float w[2][2][27];
  float S[2][2] = {{0.f, 0.f}, {0.f, 0.f}};
#pragma unroll
  for (int dq = 0; dq < 2; ++dq) {
#pragma unroll
    for (int o = 0; o < 27; ++o) {
      float2 wv = *(const float2*)(weight + o * MNK + baseg + dq * KK);
      w[dq][0][o] = wv.x; w[dq][1][o] = wv.y;
      S[dq][0] += wv.x;   S[dq][1] += wv.y;
    }
  }
  float bia[2][2], rsc[2][2];
#pragma unroll
  for (int dq = 0; dq < 2; ++dq) {
    float2 bv = *(const float2*)(bias + baseg + dq * KK);
    bia[dq][0] = bv.x; bia[dq][1] = bv.y;
    float2 rv = *(const float2*)(rscale + baseg + dq * KK);
    rsc[dq][0] = rv.x; rsc[dq][1] = rv.y;
  }

  // ---- load all 4 windows (zero-padded at grid boundary) ----
  float sI[NBATCH] = {0.f, 0.f, 0.f, 0.f}, sIq[NBATCH] = {0.f, 0.f, 0.f, 0.f};
  float sH[NBATCH] = {0.f, 0.f, 0.f, 0.f}, sHq[NBATCH] = {0.f, 0.f, 0.f, 0.f};
  for (int idx = t; idx < 1000; idx += 128) {
    int wp = idx / 100;
    int rem = idx - wp * 100;
    int wq = rem / 10;
    int wk = rem - wq * 10;
    int gm = gm0 - 1 + wp, gn = gn0 - 1 + wq, gk = gk0 - 1 + wk;
    const bool inb = (unsigned)gm < 128u && (unsigned)gn < 128u && (unsigned)gk < 128u;
    const int gbase = (gm * NN + gn) * KK + gk;
    const int adr = (wp * WIN + wq) * WSTRIDE + wk;
    const bool halo = (wp == 0 || wp == 9 || wq == 0 || wq == 9 || wk == 0 || wk == 9);
#pragma unroll
    for (int b = 0; b < NBATCH; ++b) {
      float v = 0.0f;
      if (inb) v = x[b * MNK + gbase];
      Wl[b][adr] = v;
      if (halo) { sH[b] += v; sHq[b] += v * v; }
      else      { sI[b] += v; sIq[b] += v * v; }
    }
  }
  // per-wave totals -> LDS; halo shell is static across iterations
#pragma unroll
  for (int b = 0; b < NBATCH; ++b) {
    bfly2(sI[b], sIq[b]);
    bfly2(sH[b], sHq[b]);
    if ((t & 63) == 0) {
      const int wv_ = t >> 6;
      red[0][b][wv_ * 2 + 0] = sI[b]; red[0][b][wv_ * 2 + 1] = sIq[b];
      redH[b][wv_ * 2 + 0]   = sH[b]; redH[b][wv_ * 2 + 1]   = sHq[b];
    }
  }
  __syncthreads();
  float hS[NBATCH], hQ[NBATCH];
#pragma unroll
  for (int b = 0; b < NBATCH; ++b) {
    float4 h = *(const float4*)redH[b];
    hS[b] = h.x + h.z; hQ[b] = h.y + h.w;
  }
  // own interior acts in registers (kept in sync with LDS)
  float a[NBATCH][2][2];
#pragma unroll
  for (int b = 0; b < NBATCH; ++b)
#pragma unroll
    for (int dq = 0; dq < 2; ++dq)
#pragma unroll
      for (int dr = 0; dr < 2; ++dr)
        a[b][dq][dr] = Wl[b][((p + 1) * WIN + (q0 + dq + 1)) * WSTRIDE + (r0 + dr + 1)];

  for (int it = 0; it < ITERS; ++it) {
    const int rb = it & 1;
    // ---- 4 independent conv->stats->silu chains (norm folded into epilogue) ----
#pragma unroll
    for (int b = 0; b < NBATCH; ++b) {
      float acc[2][2] = {{0.f, 0.f}, {0.f, 0.f}};
#pragma unroll
      for (int i = 0; i < 3; ++i) {
        float v[4][4];
#pragma unroll
        for (int jj = 0; jj < 4; ++jj) {
          const float* bp = &Wl[b][((p + i) * WIN + (q0 + jj)) * WSTRIDE + r0];
          float2 u0 = *(const float2*)bp;
          float2 u1 = *(const float2*)(bp + 2);
          v[jj][0] = u0.x; v[jj][1] = u0.y; v[jj][2] = u1.x; v[jj][3] = u1.y;
        }
#pragma unroll
        for (int j = 0; j < 3; ++j)
#pragma unroll
          for (int kc = 0; kc < 3; ++kc) {
            const int o = i * 9 + j * 3 + kc;
#pragma unroll
            for (int dq = 0; dq < 2; ++dq) {
              acc[dq][0] += w[dq][0][o] * v[dq + j][kc];
              acc[dq][1] += w[dq][1][o] * v[dq + j][kc + 1];
            }
          }
      }
      // stats: one float4 broadcast read (both waves' partials) + halo regs
      float4 rr = *(const float4*)&red[rb][b][0];
      const float tS = rr.x + rr.z + hS[b];
      const float tQ = rr.y + rr.w + hQ[b];
      const float mu = tS * (1.0f / 1000.0f);
      const float var = tQ * (1.0f / 1000.0f) - mu * mu;
      const float inv = __builtin_amdgcn_rsqf(var + 1e-5f);
      const float im = inv * mu;
      // acc_final = bias + inv*conv_raw - inv*mu*(sum of 27 weights)
#pragma unroll
      for (int dq = 0; dq < 2; ++dq)
#pragma unroll
        for (int dr = 0; dr < 2; ++dr) {
          float z = bia[dq][dr] + inv * acc[dq][dr] - im * S[dq][dr];
          float e = __expf(-z);
          float sg = __builtin_amdgcn_rcpf(1.0f + e);  // sigmoid(z)
          a[b][dq][dr] += rsc[dq][dr] * (z * sg);      // residual silu
        }
    }
    if (it < ITERS - 1) {
      __syncthreads();  // all window/red reads of this iter done
#pragma unroll
      for (int b = 0; b < NBATCH; ++b) {
#pragma unroll
        for (int dq = 0; dq < 2; ++dq) {
          Wl[b][((p + 1) * WIN + (q0 + dq + 1)) * WSTRIDE + (r0 + 1)] = a[b][dq][0];
          Wl[b][((p + 1) * WIN + (q0 + dq + 1)) * WSTRIDE + (r0 + 2)] = a[b][dq][1];
        }
        float ls = a[b][0][0] + a[b][0][1] + a[b][1][0] + a[b][1][1];
        float lq = a[b][0][0] * a[b][0][0] + a[b][0][1] * a[b][0][1] +
                   a[b][1][0] * a[b][1][0] + a[b][1][1] * a[b][1][1];
        bfly2(ls, lq);
        if ((t & 63) == 0) {
          const int wv_ = t >> 6;
          red[rb ^ 1][b][wv_ * 2 + 0] = ls;
          red[rb ^ 1][b][wv_ * 2 + 1] = lq;
        }
      }
      __syncthreads();  // writes + partials visible for next iteration
    }
  }
  // ---- write final interiors from registers ----
#pragma unroll
  for (int b = 0; b < NBATCH; ++b) {
    const int baseo = ((b * MM + gm0 + p) * NN + (gn0 + q0)) * KK + (gk0 + r0);
#pragma unroll
    for (int dq = 0; dq < 2; ++dq) {
      float2 ov; ov.x = a[b][dq][0]; ov.y = a[b][dq][1];
      *(float2*)(out + baseo + dq * KK) = ov;
    }
  }
}

extern "C" void kernel_launch(void* const* d_in, const int* in_sizes, int n_in,
                              void* d_out, int out_size, void* d_ws, size_t ws_size,
                              hipStream_t stream) {
  const float* weight = (const float*)d_in[0];
  const float* bias   = (const float*)d_in[1];
  const float* rscale = (const float*)d_in[2];
  const float* x      = (const float*)d_in[3];
  // d_in[4] = inner_iterations (8), d_in[5] = block_size (8): fixed by harness
  float* out = (float*)d_out;
  gridnet_kernel<<<dim3(16 * 16 * 16), dim3(128), 0, stream>>>(
      weight, bias, rscale, x, out);
}